// Round 16
// baseline (253.255 us; speedup 1.0000x reference)
//
#include <hip/hip_runtime.h>
#include <hip/hip_fp16.h>

// RipEncoding, round 16: 4-dispatch pipeline.
//  build_all (+proj blocks, +dup l2∈{2,3})  ->  pool_hN<3,4> (+dup l2∈{4,5})
//  ->  interp8  ->  fixup2 (segmented lists, no global atomic).
//
// ws layout: [0, 332928000)            fp16 pyramid (10 x 1020x1020 x 16 halfs)
//            [332928000, +18432000)    dup region (10 x 240x240 px, x-shifted)
//            [351360000, +41943040)    float4 proj table [v][n]
//            [393303104, +10485760)    fixup pair lists (1024 segs x 2560)
//            [403788864, +4096)        per-segment counts

#define NV 10
#define FD 16
#define NS 262144          // 2^18
#define HALF_NS 131072     // 2^17
#define PYR_PX 1040400L    // 1020*1020 pixels per vertex
#define DUP0_PX 10404000   // = NV*PYR_PX, pixel index where dup region starts
#define DUP_VPX 57600      // 240*240 dup pixels per vertex
#define OFF_PL   351360000L
#define OFF_LIST 393303104L
#define OFF_CNTS 403788864L

__constant__ float c_P[NV][2][3] = {
  {{-0.7071067811865476f, 0.7071067811865476f, 0.0f},
   {-0.4082482904638631f,-0.4082482904638631f, 0.8164965809277261f}},
  {{-0.7071067811865476f, 0.7071067811865476f, 0.0f},
   { 0.4082482904638631f, 0.4082482904638631f, 0.8164965809277261f}},
  {{ 0.7071067811865476f, 0.7071067811865476f, 0.0f},
   {-0.4082482904638631f, 0.4082482904638631f, 0.8164965809277261f}},
  {{ 0.7071067811865476f, 0.7071067811865476f, 0.0f},
   { 0.4082482904638631f,-0.4082482904638631f, 0.8164965809277261f}},
  {{-1.0f, 0.0f, 0.0f},
   { 0.0f,-0.3568220897730899f, 0.9341723589627157f}},
  {{-1.0f, 0.0f, 0.0f},
   { 0.0f, 0.3568220897730899f, 0.9341723589627157f}},
  {{ 0.0f, 1.0f, 0.0f},
   {-0.9341723589627157f, 0.0f, 0.3568220897730899f}},
  {{ 0.0f, 1.0f, 0.0f},
   { 0.9341723589627157f, 0.0f, 0.3568220897730899f}},
  {{-0.3568220897730899f, 0.9341723589627157f, 0.0f},
   { 0.0f, 0.0f, 1.0f}},
  {{ 0.3568220897730899f, 0.9341723589627157f, 0.0f},
   { 0.0f, 0.0f, 1.0f}},
};

__constant__ int c_CW[8] = {0, 512, 768, 896, 960, 992, 1008, 1016};

__device__ __forceinline__ int offp_a(int l1, int l2) {
  return 1044480 - (1020 << (10 - l1)) + ((1024 - (1024 >> l2)) << (9 - l1));
}

__device__ __forceinline__ uint4 havg(uint4 a, uint4 c, __half2 hhalf) {
  uint4 res;
  __half2* rr = (__half2*)&res;
  const __half2* ha = (const __half2*)&a;
  const __half2* hc = (const __half2*)&c;
  #pragma unroll
  for (int j = 0; j < 4; ++j) rr[j] = __hmul2(__hadd2(ha[j], hc[j]), hhalf);
  return res;
}

// ---- build_all: blocks [0,2560) build pyramid; [2560,3584) do proj ----
__global__ __launch_bounds__(256) void build_all(const float* __restrict__ fm,
                                                 __half* __restrict__ pyr,
                                                 const float* __restrict__ means,
                                                 const float* __restrict__ covs,
                                                 float4* __restrict__ pl,
                                                 int* __restrict__ list,
                                                 int* __restrict__ cnts)
{
  __shared__ uint4 ldsA[2048];
  __shared__ uint4 ldsB[1024];
  __shared__ int lcnt;
  int bid = blockIdx.x;
  int t = threadIdx.x;

  if (bid >= NV * 256) {
    // ---- proj block ----
    int b2 = bid - NV * 256;           // 0..1023
    int* lbuf = (int*)ldsA;            // aliased; proj blocks don't stage
    if (t == 0) lcnt = 0;
    __syncthreads();
    int n = b2 * 256 + t;              // NS = 1024*256 exactly
    float m0 = means[3 * n], m1 = means[3 * n + 1], m2 = means[3 * n + 2];
    const float* C = covs + 9L * n;
    float c0 = C[0], c1 = C[1], c2 = C[2];
    float c3 = C[3], c4 = C[4], c5 = C[5];
    float c6 = C[6], c7 = C[7], c8 = C[8];
    #pragma unroll
    for (int v = 0; v < NV; ++v) {
      float p00 = c_P[v][0][0], p01 = c_P[v][0][1], p02 = c_P[v][0][2];
      float p10 = c_P[v][1][0], p11 = c_P[v][1][1], p12 = c_P[v][1][2];
      float cx = m0 * p00 + m1 * p01 + m2 * p02;
      float cy = m0 * p10 + m1 * p11 + m2 * p12;
      float t0 = c0 * p00 + c1 * p01 + c2 * p02;
      float t1 = c3 * p00 + c4 * p01 + c5 * p02;
      float t2 = c6 * p00 + c7 * p01 + c8 * p02;
      float s2x = p00 * t0 + p01 * t1 + p02 * t2;
      t0 = c0 * p10 + c1 * p11 + c2 * p12;
      t1 = c3 * p10 + c4 * p11 + c5 * p12;
      t2 = c6 * p10 + c7 * p11 + c8 * p12;
      float s2y = p10 * t0 + p11 * t1 + p12 * t2;
      float lx = 0.5f * log2f(fmaxf(s2x, 1e-20f)) + 9.0f;
      float ly = 0.5f * log2f(fmaxf(s2y, 1e-20f)) + 9.0f;
      lx = fminf(fmaxf(lx, 0.0f), 7.0f);
      ly = fminf(fmaxf(ly, 0.0f), 7.0f);
      pl[(long)v * NS + n] = make_float4(cx, cy, lx, ly);
      if (lx < 1.0f || ly < 1.0f) {
        int pos = atomicAdd(&lcnt, 1);
        lbuf[pos] = v * NS + n;
      }
    }
    __syncthreads();
    if (t == 0) cnts[b2] = lcnt;
    for (int i = t; i < lcnt; i += 256) list[b2 * 2560 + i] = lbuf[i];
    return;
  }

  // ---- build block: one per (v, 8-row band, 128-px strip) ----
  int v = bid >> 8;
  int rem = bid & 255;
  int b = rem >> 2;
  int s = rem & 3;

  __half* bv = pyr + (long)v * PYR_PX * FD;
  uint4* bv4 = (uint4*)bv;
  const __half2 hhalf = __floats2half2_rn(0.5f, 0.5f);
  const long dupRel = (long)DUP0_PX + (long)v * DUP_VPX - (long)v * PYR_PX;

  {
    const float4* src = (const float4*)(fm +
        (((long)v * 512 + b * 8) * 512 + s * 128) * FD);
    uint2* ldsu2 = (uint2*)ldsA;
    #pragma unroll
    for (int i = 0; i < 16; ++i) {
      int u = t + 256 * i;
      int r = u >> 9;
      int f4 = u & 511;
      int px = f4 >> 2, qq = f4 & 3;
      float4 d = src[(long)r * 2048 + f4];
      __half2 h0 = __floats2half2_rn(d.x, d.y);
      __half2 h1 = __floats2half2_rn(d.z, d.w);
      uint2 val;
      val.x = *(unsigned*)&h0; val.y = *(unsigned*)&h1;
      ldsu2[(r * 128 + px) * 4 + qq] = val;
    }
  }
  __syncthreads();

  #pragma unroll
  for (int l1 = 0; l1 < 8; ++l1) {
    uint4* cur = (l1 & 1) ? ldsB : ldsA;
    const int Wc = 128 >> l1;

    if (l1 < 7) {
      uint4* nxt = (l1 & 1) ? ldsA : ldsB;
      const int Wn = Wc >> 1;
      const int units = 8 * Wn * 2;
      for (int u = t; u < units; u += 256) {
        int k = u & 1;
        int xr = u >> 1;
        int x = xr & (Wn - 1);
        int r = xr >> (6 - l1);
        uint4 a = cur[(r * Wc + 2 * x) * 2 + k];
        uint4 c = cur[(r * Wc + 2 * x + 1) * 2 + k];
        nxt[(r * Wn + x) * 2 + k] = havg(a, c, hhalf);
      }
    }

    if (l1 >= 1) {
      const int slots = Wc * 2;
      if (t < slots) {
        int k = t & 1, x = t >> 1;
        const int Wg = 512 >> l1;
        uint4 r0 = cur[(0 * Wc + x) * 2 + k];
        uint4 r1 = cur[(1 * Wc + x) * 2 + k];
        uint4 r2 = cur[(2 * Wc + x) * 2 + k];
        uint4 r3 = cur[(3 * Wc + x) * 2 + k];
        uint4 r4 = cur[(4 * Wc + x) * 2 + k];
        uint4 r5 = cur[(5 * Wc + x) * 2 + k];
        uint4 r6 = cur[(6 * Wc + x) * 2 + k];
        uint4 r7 = cur[(7 * Wc + x) * 2 + k];
        uint4 a0 = havg(r0, r1, hhalf), a1 = havg(r2, r3, hhalf);
        uint4 a2 = havg(r4, r5, hhalf), a3 = havg(r6, r7, hhalf);
        uint4 b0 = havg(a0, a1, hhalf), b1 = havg(a2, a3, hhalf);
        uint4 c0 = havg(b0, b1, hhalf);
        int gx = s * Wc + x;
        long p1 = (long)offp_a(l1, 1) + (long)(b * 4) * Wg + gx;
        bv4[p1 * 2 + k] = a0;
        bv4[(p1 + Wg) * 2 + k] = a1;
        bv4[(p1 + 2 * Wg) * 2 + k] = a2;
        bv4[(p1 + 3 * Wg) * 2 + k] = a3;
        long p2 = (long)offp_a(l1, 2) + (long)(b * 2) * Wg + gx;
        bv4[p2 * 2 + k] = b0;
        bv4[(p2 + Wg) * 2 + k] = b1;
        long p3 = (long)offp_a(l1, 3) + (long)b * Wg + gx;
        bv4[p3 * 2 + k] = c0;

        // dup writes for l1 in [2,5], l2 in {2,3}: dup[y][x-1] = plane[y][x]
        if ((unsigned)(l1 - 2) <= 3u) {
          int Ad = 61440 - (245760 >> l1);
          int sh = 9 - l1;
          // l2=2: Bd=0 rows 2b,2b+1 ; l2=3: Bd=128 row b
          if (gx >= 1) {
            bv4[(dupRel + Ad + ((long)(2 * b) << sh) + gx - 1) * 2 + k] = b0;
            bv4[(dupRel + Ad + ((long)(2 * b + 1) << sh) + gx - 1) * 2 + k] = b1;
            bv4[(dupRel + Ad + ((long)(128 + b) << sh) + gx - 1) * 2 + k] = c0;
          }
          if (gx == Wg - 1) {
            bv4[(dupRel + Ad + ((long)(2 * b) << sh) + gx) * 2 + k] = b0;
            bv4[(dupRel + Ad + ((long)(2 * b + 1) << sh) + gx) * 2 + k] = b1;
            bv4[(dupRel + Ad + ((long)(128 + b) << sh) + gx) * 2 + k] = c0;
          }
        }
      }
    }
    __syncthreads();
  }
}

// ---- pool tail: levels (l1,4..7) from (l1,3), l1>=1; dup for l2 in {4,5} ----
template<int L2SRC, int NLEV>
__global__ __launch_bounds__(256) void pool_hN(__half* __restrict__ pyr)
{
  constexpr int R = 1 << NLEV;
  constexpr int HL = 512 >> (L2SRC + NLEV);
  int total = NV * HL * 1016;
  int t = blockIdx.x * 256 + threadIdx.x;
  if (t >= total) return;
  int u = t % 1016;
  int r2 = t / 1016;
  int c = 512 + (u >> 1), k = u & 1;
  int y = r2 % HL;
  int v = r2 / HL;
  int l1 = 0;
  #pragma unroll
  for (int i = 1; i < 8; ++i) l1 += (c >= c_CW[i]) ? 1 : 0;
  int x = c - c_CW[l1];
  int W = 512 >> l1;
  __half* bv = pyr + (long)v * PYR_PX * FD;
  const __half* src = bv + (long)offp_a(l1, L2SRC) * FD;
  const long dupRel = (long)DUP0_PX + (long)v * DUP_VPX - (long)v * PYR_PX;
  bool dupl1 = ((unsigned)(l1 - 2) <= 3u);
  int Ad = 61440 - (245760 >> l1);
  int sh = 9 - l1;

  uint4 d[R];
  long base = ((long)(y * R) * W + x) * FD + k * 8;
  #pragma unroll
  for (int r = 0; r < R; ++r)
    d[r] = *(const uint4*)(src + base + (long)r * W * FD);

  const __half2 hhalf = __floats2half2_rn(0.5f, 0.5f);
  #pragma unroll
  for (int lev = 1; lev <= NLEV; ++lev) {
    int cnt = R >> lev;
    int l2g = L2SRC + lev;
    __half* dst = bv + (long)offp_a(l1, l2g) * FD;
    int Bd = 256 - (1024 >> l2g);
    #pragma unroll
    for (int r = 0; r < cnt; ++r) {
      d[r] = havg(d[2 * r], d[2 * r + 1], hhalf);
      int yy = y * cnt + r;
      *(uint4*)(dst + (((long)yy) * W + x) * FD + k * 8) = d[r];
      if (dupl1 && l2g <= 5) {
        if (x >= 1)
          ((uint4*)bv)[(dupRel + Ad + ((long)(Bd + yy) << sh) + x - 1) * 2 + k] = d[r];
        if (x == W - 1)
          ((uint4*)bv)[(dupRel + Ad + ((long)(Bd + yy) << sh) + x) * 2 + k] = d[r];
      }
    }
  }
}

// ---- per-pair tap context (fast path) ----
struct Ctx {
  int oA, oB, oC, oD, oE, oF, oG, oH;
  __half2 wA, wB, wC, wD, wE, wF, wG, wH;
};

__device__ __forceinline__ Ctx mk_ctx(const float4 p, const bool qodd,
                                      const int dupRel)
{
  Ctx c;
  float cx = p.x, cy = p.y, lx = p.z, ly = p.w;
  int l1f = (int)lx, l2f = (int)ly;
  float wx = lx - (float)l1f, wy = ly - (float)l2f;
  int l1c = min(l1f + 1, 7);
  int l2c = min(l2f + 1, 7);

  int sh_0 = 9 - l1f;
  int Ar_0 = 1044480 - (1020 << (10 - l1f));
  float u0 = (cx * 0.5f + 0.5f) * (float)(1 << sh_0) - 0.5f;
  float uf0 = floorf(u0);
  float fu0 = u0 - uf0;
  int iu0 = (int)uf0;
  bool e0 = (iu0 < 0) || (iu0 >= (1 << sh_0) - 1);
  int ix_0 = min(max(iu0, 0), (1 << sh_0) - 1);
  float wxl_0 = qodd ? (e0 ? 0.0f : fu0) : (e0 ? 1.0f : 1.0f - fu0);
  int pOdd_0 = ix_0 & 1;
  int Ad_0 = 61440 - (245760 >> l1f);
  int inR1_0 = ((unsigned)(l1f - 2) <= 3u) ? 1 : 0;

  int sh_1 = 9 - l1c;
  int Ar_1 = 1044480 - (1020 << (10 - l1c));
  float u1 = (cx * 0.5f + 0.5f) * (float)(1 << sh_1) - 0.5f;
  float uf1 = floorf(u1);
  float fu1 = u1 - uf1;
  int iu1 = (int)uf1;
  bool e1 = (iu1 < 0) || (iu1 >= (1 << sh_1) - 1);
  int ix_1 = min(max(iu1, 0), (1 << sh_1) - 1);
  float wxl_1 = qodd ? (e1 ? 0.0f : fu1) : (e1 ? 1.0f : 1.0f - fu1);
  int pOdd_1 = ix_1 & 1;
  int Ad_1 = 61440 - (245760 >> l1c);
  int inR1_1 = ((unsigned)(l1c - 2) <= 3u) ? 1 : 0;

  float wl1_0 = 1.0f - wx, wl1_1 = wx;

  int H0 = 512 >> l2f;
  float vv0 = (cy * 0.5f + 0.5f) * (float)H0 - 0.5f;
  float vf0 = floorf(vv0);
  float fv_0 = vv0 - vf0;
  int iv0 = (int)vf0;
  int iy_0 = min(max(iv0, 0), H0 - 1);
  int dy_0 = min(max(iv0 + 1, 0), H0 - 1) - iy_0;
  int Bv_0 = 1024 - (1024 >> l2f);
  int Bd_0 = 256 - (1024 >> l2f);
  int inR2_0 = ((unsigned)(l2f - 2) <= 3u) ? 1 : 0;

  int H1 = 512 >> l2c;
  float vv1 = (cy * 0.5f + 0.5f) * (float)H1 - 0.5f;
  float vf1 = floorf(vv1);
  float fv_1 = vv1 - vf1;
  int iv1 = (int)vf1;
  int iy_1 = min(max(iv1, 0), H1 - 1);
  int dy_1 = min(max(iv1 + 1, 0), H1 - 1) - iy_1;
  int Bv_1 = 1024 - (1024 >> l2c);
  int Bd_1 = 256 - (1024 >> l2c);
  int inR2_1 = ((unsigned)(l2c - 2) <= 3u) ? 1 : 0;

  float wl2_0 = 1.0f - wy, wl2_1 = wy;

  bool s00 = pOdd_0 && inR1_0 && inR2_0;
  c.oA = s00 ? (dupRel + Ad_0 + ((Bd_0 + iy_0) << sh_0) + ix_0 - 1)
             : (Ar_0 + ((Bv_0 + iy_0) << sh_0) + ix_0);
  c.oB = c.oA + (dy_0 << sh_0);
  bool s01 = pOdd_0 && inR1_0 && inR2_1;
  c.oC = s01 ? (dupRel + Ad_0 + ((Bd_1 + iy_1) << sh_0) + ix_0 - 1)
             : (Ar_0 + ((Bv_1 + iy_1) << sh_0) + ix_0);
  c.oD = c.oC + (dy_1 << sh_0);
  bool s10 = pOdd_1 && inR1_1 && inR2_0;
  c.oE = s10 ? (dupRel + Ad_1 + ((Bd_0 + iy_0) << sh_1) + ix_1 - 1)
             : (Ar_1 + ((Bv_0 + iy_0) << sh_1) + ix_1);
  c.oF = c.oE + (dy_0 << sh_1);
  bool s11 = pOdd_1 && inR1_1 && inR2_1;
  c.oG = s11 ? (dupRel + Ad_1 + ((Bd_1 + iy_1) << sh_1) + ix_1 - 1)
             : (Ar_1 + ((Bv_1 + iy_1) << sh_1) + ix_1);
  c.oH = c.oG + (dy_1 << sh_1);

  float wb00 = wl1_0 * wl2_0 * wxl_0;
  float wb01 = wl1_0 * wl2_1 * wxl_0;
  float wb10 = wl1_1 * wl2_0 * wxl_1;
  float wb11 = wl1_1 * wl2_1 * wxl_1;
  c.wA = __float2half2_rn(wb00 * (1.0f - fv_0));
  c.wB = __float2half2_rn(wb00 * fv_0);
  c.wC = __float2half2_rn(wb01 * (1.0f - fv_1));
  c.wD = __float2half2_rn(wb01 * fv_1);
  c.wE = __float2half2_rn(wb10 * (1.0f - fv_0));
  c.wF = __float2half2_rn(wb10 * fv_0);
  c.wG = __float2half2_rn(wb11 * (1.0f - fv_1));
  c.wH = __float2half2_rn(wb11 * fv_1);

  __half2 z = __float2half2_rn(0.0f);
  if (l1f == 0) { c.wA = z; c.wB = z; c.wC = z; c.wD = z; }
  if (l2f == 0) { c.wA = z; c.wB = z; c.wE = z; c.wF = z; }
  return c;
}

// ---- interp: 4 lanes/pair, 2 pairs/thread ----
__global__ __launch_bounds__(256) void interp8(const float4* __restrict__ pl,
                                               const __half* __restrict__ pyr,
                                               float* __restrict__ out)
{
  int bid = blockIdx.x;
  int swz = (bid & 7) * 2560 + (bid >> 3);
  int t = swz * 256 + threadIdx.x;
  int q = t & 3;
  bool qodd = (q & 1);
  int vlow = (t >> 2) & 1;
  int n = (t >> 3) & (HALF_NS - 1);
  int v2 = t >> 20;
  int v = v2 * 2 + vlow;
  int nA = n, nB = n + HALF_NS;
  int dupRel = DUP0_PX + v * DUP_VPX - v * 1040400;

  float4 pA = pl[(long)v * NS + nA];
  float4 pB = pl[(long)v * NS + nB];

  const __half* bvq = pyr + (long)v * PYR_PX * FD + ((q & 1) * 16 + (q >> 1) * 8);

  Ctx cA = mk_ctx(pA, qodd, dupRel);
  uint4 dAA = *(const uint4*)(bvq + (long)cA.oA * FD);
  uint4 dAB = *(const uint4*)(bvq + (long)cA.oB * FD);
  uint4 dAC = *(const uint4*)(bvq + (long)cA.oC * FD);
  uint4 dAD = *(const uint4*)(bvq + (long)cA.oD * FD);
  uint4 dAE = *(const uint4*)(bvq + (long)cA.oE * FD);
  uint4 dAF = *(const uint4*)(bvq + (long)cA.oF * FD);
  uint4 dAG = *(const uint4*)(bvq + (long)cA.oG * FD);
  uint4 dAH = *(const uint4*)(bvq + (long)cA.oH * FD);

  Ctx cB = mk_ctx(pB, qodd, dupRel);
  uint4 dBA = *(const uint4*)(bvq + (long)cB.oA * FD);
  uint4 dBB = *(const uint4*)(bvq + (long)cB.oB * FD);
  uint4 dBC = *(const uint4*)(bvq + (long)cB.oC * FD);
  uint4 dBD = *(const uint4*)(bvq + (long)cB.oD * FD);
  uint4 dBE = *(const uint4*)(bvq + (long)cB.oE * FD);
  uint4 dBF = *(const uint4*)(bvq + (long)cB.oF * FD);
  uint4 dBG = *(const uint4*)(bvq + (long)cB.oG * FD);
  uint4 dBH = *(const uint4*)(bvq + (long)cB.oH * FD);
  __builtin_amdgcn_sched_barrier(0);

  __half2 z = __float2half2_rn(0.0f);
  __half2 aA0 = z, aA1 = z, aA2 = z, aA3 = z;
  __half2 aB0 = z, aB1 = z, aB2 = z, aB3 = z;
  #define ACC8(A0, A1, A2, A3, D, W) { const __half2* hh = (const __half2*)&(D); \
    A0 = __hfma2(hh[0], (W), A0); A1 = __hfma2(hh[1], (W), A1);                   \
    A2 = __hfma2(hh[2], (W), A2); A3 = __hfma2(hh[3], (W), A3); }
  ACC8(aA0,aA1,aA2,aA3, dAA, cA.wA) ACC8(aA0,aA1,aA2,aA3, dAB, cA.wB)
  ACC8(aA0,aA1,aA2,aA3, dAC, cA.wC) ACC8(aA0,aA1,aA2,aA3, dAD, cA.wD)
  ACC8(aA0,aA1,aA2,aA3, dAE, cA.wE) ACC8(aA0,aA1,aA2,aA3, dAF, cA.wF)
  ACC8(aA0,aA1,aA2,aA3, dAG, cA.wG) ACC8(aA0,aA1,aA2,aA3, dAH, cA.wH)
  ACC8(aB0,aB1,aB2,aB3, dBA, cB.wA) ACC8(aB0,aB1,aB2,aB3, dBB, cB.wB)
  ACC8(aB0,aB1,aB2,aB3, dBC, cB.wC) ACC8(aB0,aB1,aB2,aB3, dBD, cB.wD)
  ACC8(aB0,aB1,aB2,aB3, dBE, cB.wE) ACC8(aB0,aB1,aB2,aB3, dBF, cB.wF)
  ACC8(aB0,aB1,aB2,aB3, dBG, cB.wG) ACC8(aB0,aB1,aB2,aB3, dBH, cB.wH)
  #undef ACC8

  #define XC(A0, A1, A2, A3) {                                   \
    int x0 = *(int*)&A0, x1 = *(int*)&A1;                        \
    int x2 = *(int*)&A2, x3 = *(int*)&A3;                        \
    int y0 = __shfl_xor(x0, 1), y1 = __shfl_xor(x1, 1);          \
    int y2 = __shfl_xor(x2, 1), y3 = __shfl_xor(x3, 1);          \
    A0 = __hadd2(A0, *(__half2*)&y0); A1 = __hadd2(A1, *(__half2*)&y1); \
    A2 = __hadd2(A2, *(__half2*)&y2); A3 = __hadd2(A3, *(__half2*)&y3); }
  XC(aA0, aA1, aA2, aA3)
  XC(aB0, aB1, aB2, aB3)
  #undef XC

  __half2 sA0 = qodd ? aA2 : aA0;
  __half2 sA1 = qodd ? aA3 : aA1;
  float2 fA0 = __half22float2(sA0);
  float2 fA1 = __half22float2(sA1);
  *(float4*)(out + ((long)nA * NV + v) * FD + q * 4) =
      make_float4(fA0.x, fA0.y, fA1.x, fA1.y);

  __half2 sB0 = qodd ? aB2 : aB0;
  __half2 sB1 = qodd ? aB3 : aB1;
  float2 fB0 = __half22float2(sB0);
  float2 fB1 = __half22float2(sB1);
  *(float4*)(out + ((long)nB * NV + v) * FD + q * 4) =
      make_float4(fB0.x, fB0.y, fB1.x, fB1.y);
}

// ---- fixup2: segmented lists, 4 waves per segment ----
__global__ __launch_bounds__(256) void fixup2(const float4* __restrict__ pl,
                                              const __half* __restrict__ pyr,
                                              const float* __restrict__ fm,
                                              const int* __restrict__ cnts,
                                              const int* __restrict__ list,
                                              float* __restrict__ out)
{
  int lane = threadIdx.x & 63;
  int wid = (blockIdx.x * 256 + threadIdx.x) >> 6;   // 0..4095
  int seg = wid >> 2;                                 // 0..1023
  int sub = wid & 3;
  int nfix = cnts[seg];
  int k  = lane & 1;
  int h  = (lane >> 1) & 1;
  int xs = (lane >> 2) & 1;
  int r  = (lane >> 3) & 1;
  int jj = (lane >> 4) & 1;
  int ii = (lane >> 5) & 1;

  for (int idx = sub; idx < nfix; idx += 4) {
    int pv = list[seg * 2560 + idx];
    int v = pv >> 18, n = pv & (NS - 1);
    float4 p = pl[(long)pv];
    float cx = p.x, cy = p.y, lx = p.z, ly = p.w;
    int l1f = (int)lx, l2f = (int)ly;
    float wx = lx - (float)l1f, wy = ly - (float)l2f;
    int l1 = ii ? min(l1f + 1, 7) : l1f;
    int l2 = jj ? min(l2f + 1, 7) : l2f;
    float wl1 = ii ? wx : 1.0f - wx;
    float wl2 = jj ? wy : 1.0f - wy;
    int Wl = 512 >> l1, Hl = 512 >> l2;

    float u = (cx * 0.5f + 0.5f) * (float)Wl - 0.5f;
    float uf = floorf(u);
    float fu = u - uf;
    int iu = (int)uf;
    int ix0 = min(max(iu, 0), Wl - 1);
    int ix1 = min(max(iu + 1, 0), Wl - 1);
    int ix = xs ? ix1 : ix0;
    float wxs = xs ? fu : 1.0f - fu;

    float vv = (cy * 0.5f + 0.5f) * (float)Hl - 0.5f;
    float vf = floorf(vv);
    float fv = vv - vf;
    int iv = (int)vf;
    int iy0 = min(max(iv, 0), Hl - 1);
    int iy1 = min(max(iv + 1, 0), Hl - 1);
    int iy = r ? iy1 : iy0;
    float wys = r ? fv : 1.0f - fv;

    float w = wl1 * wl2 * wxs * wys;
    float s0=0,s1=0,s2=0,s3=0,s4=0,s5=0,s6=0,s7=0;

    const float* fmb = fm + (long)v * (262144L * FD) + h * 8;
    if (l1 > 0 && l2 > 0) {
      if (k == 0) {
        const __half* pp = pyr + ((long)v * PYR_PX + offp_a(l1, l2) +
                                  (long)iy * Wl + ix) * FD + h * 8;
        uint4 d = *(const uint4*)pp;
        const __half2* hh = (const __half2*)&d;
        float2 f0 = __half22float2(hh[0]), f1 = __half22float2(hh[1]);
        float2 f2 = __half22float2(hh[2]), f3 = __half22float2(hh[3]);
        s0=f0.x; s1=f0.y; s2=f1.x; s3=f1.y; s4=f2.x; s5=f2.y; s6=f3.x; s7=f3.y;
      }
    } else if (l1 == 0 && l2 == 0) {
      if (k == 0) {
        const float* s = fmb + ((long)iy * 512 + ix) * FD;
        float4 g0 = *(const float4*)s, g1 = *(const float4*)(s + 4);
        s0=g0.x; s1=g0.y; s2=g0.z; s3=g0.w; s4=g1.x; s5=g1.y; s6=g1.z; s7=g1.w;
      }
    } else if (l2 == 0) {
      int m = 1 << l1, base = ix << l1;
      for (int e = k; e < m; e += 2) {
        const float* s = fmb + ((long)iy * 512 + base + e) * FD;
        float4 g0 = *(const float4*)s, g1 = *(const float4*)(s + 4);
        s0+=g0.x; s1+=g0.y; s2+=g0.z; s3+=g0.w;
        s4+=g1.x; s5+=g1.y; s6+=g1.z; s7+=g1.w;
      }
      float inv = 1.0f / (float)m;
      s0*=inv; s1*=inv; s2*=inv; s3*=inv; s4*=inv; s5*=inv; s6*=inv; s7*=inv;
    } else {
      int m = 1 << l2, base = iy << l2;
      for (int e = k; e < m; e += 2) {
        const float* s = fmb + ((long)(base + e) * 512 + ix) * FD;
        float4 g0 = *(const float4*)s, g1 = *(const float4*)(s + 4);
        s0+=g0.x; s1+=g0.y; s2+=g0.z; s3+=g0.w;
        s4+=g1.x; s5+=g1.y; s6+=g1.z; s7+=g1.w;
      }
      float inv = 1.0f / (float)m;
      s0*=inv; s1*=inv; s2*=inv; s3*=inv; s4*=inv; s5*=inv; s6*=inv; s7*=inv;
    }

    float a0=w*s0, a1=w*s1, a2=w*s2, a3=w*s3;
    float a4=w*s4, a5=w*s5, a6=w*s6, a7=w*s7;

    #define RED(M) { a0 += __shfl_xor(a0, M); a1 += __shfl_xor(a1, M); \
      a2 += __shfl_xor(a2, M); a3 += __shfl_xor(a3, M);                \
      a4 += __shfl_xor(a4, M); a5 += __shfl_xor(a5, M);                \
      a6 += __shfl_xor(a6, M); a7 += __shfl_xor(a7, M); }
    RED(1) RED(4) RED(8) RED(16) RED(32)
    #undef RED

    if (lane == 0 || lane == 2) {         // h = 0 / 1
      float* o = out + ((long)n * NV + v) * FD + h * 8;
      *(float4*)o = make_float4(a0, a1, a2, a3);
      *(float4*)(o + 4) = make_float4(a4, a5, a6, a7);
    }
  }
}

extern "C" void kernel_launch(void* const* d_in, const int* in_sizes, int n_in,
                              void* d_out, int out_size, void* d_ws, size_t ws_size,
                              hipStream_t stream)
{
  const float* means = (const float*)d_in[0];
  const float* covs  = (const float*)d_in[1];
  const float* fm    = (const float*)d_in[2];
  float* out = (float*)d_out;
  __half* pyr = (__half*)d_ws;
  float4* pl  = (float4*)((char*)d_ws + OFF_PL);
  int* list   = (int*)((char*)d_ws + OFF_LIST);
  int* cnts   = (int*)((char*)d_ws + OFF_CNTS);

  build_all<<<NV * 256 + 1024, 256, 0, stream>>>(fm, pyr, means, covs,
                                                 pl, list, cnts);
  {
    int tB = NV * 4 * 1016;    // levels 4..7 from 3 (l1>=1), single launch
    pool_hN<3, 4><<<(tB + 255) / 256, 256, 0, stream>>>(pyr);
  }
  interp8<<<20480, 256, 0, stream>>>(pl, pyr, out);
  fixup2<<<1024, 256, 0, stream>>>(pl, pyr, fm, cnts, list, out);
}

// Round 17
// 237.032 us; speedup vs baseline: 1.0684x; 1.0684x over previous
//
#include <hip/hip_runtime.h>
#include <hip/hip_fp16.h>

// RipEncoding, round 17: revert to round-15 structure (verified best, 237 µs).
// build_all (zeroes cnt) -> pool_hN<3,4> -> build_dup -> proj -> interp8 -> fixup2.
//
// ws layout: [0, 332928000)            fp16 pyramid (10 x 1020x1020 x 16 halfs)
//            [332928000, +18432000)    dup region (10 x 240x240 px, x-shifted)
//            [351360000, +41943040)    float4 proj table [v][n]
//            [393303040, 4)            fixup counter
//            [393303104, +10485760)    fixup pair list

#define NV 10
#define FD 16
#define NS 262144          // 2^18
#define HALF_NS 131072     // 2^17
#define PYR_PX 1040400L    // 1020*1020 pixels per vertex
#define DUP0_PX 10404000   // = NV*PYR_PX, pixel index where dup region starts
#define DUP_VPX 57600      // 240*240 dup pixels per vertex
#define OFF_PL   351360000L
#define OFF_CNT  393303040L
#define OFF_LIST 393303104L

__constant__ float c_P[NV][2][3] = {
  {{-0.7071067811865476f, 0.7071067811865476f, 0.0f},
   {-0.4082482904638631f,-0.4082482904638631f, 0.8164965809277261f}},
  {{-0.7071067811865476f, 0.7071067811865476f, 0.0f},
   { 0.4082482904638631f, 0.4082482904638631f, 0.8164965809277261f}},
  {{ 0.7071067811865476f, 0.7071067811865476f, 0.0f},
   {-0.4082482904638631f, 0.4082482904638631f, 0.8164965809277261f}},
  {{ 0.7071067811865476f, 0.7071067811865476f, 0.0f},
   { 0.4082482904638631f,-0.4082482904638631f, 0.8164965809277261f}},
  {{-1.0f, 0.0f, 0.0f},
   { 0.0f,-0.3568220897730899f, 0.9341723589627157f}},
  {{-1.0f, 0.0f, 0.0f},
   { 0.0f, 0.3568220897730899f, 0.9341723589627157f}},
  {{ 0.0f, 1.0f, 0.0f},
   {-0.9341723589627157f, 0.0f, 0.3568220897730899f}},
  {{ 0.0f, 1.0f, 0.0f},
   { 0.9341723589627157f, 0.0f, 0.3568220897730899f}},
  {{-0.3568220897730899f, 0.9341723589627157f, 0.0f},
   { 0.0f, 0.0f, 1.0f}},
  {{ 0.3568220897730899f, 0.9341723589627157f, 0.0f},
   { 0.0f, 0.0f, 1.0f}},
};

__constant__ int c_CW[8] = {0, 512, 768, 896, 960, 992, 1008, 1016};

__device__ __forceinline__ int offp_a(int l1, int l2) {
  return 1044480 - (1020 << (10 - l1)) + ((1024 - (1024 >> l2)) << (9 - l1));
}

__device__ __forceinline__ uint4 havg(uint4 a, uint4 c, __half2 hhalf) {
  uint4 res;
  __half2* rr = (__half2*)&res;
  const __half2* ha = (const __half2*)&a;
  const __half2* hc = (const __half2*)&c;
  #pragma unroll
  for (int j = 0; j < 4; ++j) rr[j] = __hmul2(__hadd2(ha[j], hc[j]), hhalf);
  return res;
}

// ---- fused build: one block per (v, 8-row band, 128-px strip) ----
// Materializes ONLY planes with l1>=1 && l2 in [1,3]. Also zeroes *cnt.
__global__ __launch_bounds__(256) void build_all(const float* __restrict__ fm,
                                                 __half* __restrict__ pyr,
                                                 int* __restrict__ cnt)
{
  __shared__ uint4 ldsA[2048];
  __shared__ uint4 ldsB[1024];
  int bid = blockIdx.x;
  if (bid == 0 && threadIdx.x == 0) *cnt = 0;
  int v = bid >> 8;
  int rem = bid & 255;
  int b = rem >> 2;
  int s = rem & 3;
  int t = threadIdx.x;

  __half* bv = pyr + (long)v * PYR_PX * FD;
  uint4* bv4 = (uint4*)bv;
  const __half2 hhalf = __floats2half2_rn(0.5f, 0.5f);

  {
    const float4* src = (const float4*)(fm +
        (((long)v * 512 + b * 8) * 512 + s * 128) * FD);
    uint2* ldsu2 = (uint2*)ldsA;
    #pragma unroll
    for (int i = 0; i < 16; ++i) {
      int u = t + 256 * i;
      int r = u >> 9;
      int f4 = u & 511;
      int px = f4 >> 2, qq = f4 & 3;
      float4 d = src[(long)r * 2048 + f4];
      __half2 h0 = __floats2half2_rn(d.x, d.y);
      __half2 h1 = __floats2half2_rn(d.z, d.w);
      uint2 val;
      val.x = *(unsigned*)&h0; val.y = *(unsigned*)&h1;
      ldsu2[(r * 128 + px) * 4 + qq] = val;
    }
  }
  __syncthreads();

  #pragma unroll
  for (int l1 = 0; l1 < 8; ++l1) {
    uint4* cur = (l1 & 1) ? ldsB : ldsA;
    const int Wc = 128 >> l1;

    if (l1 < 7) {
      uint4* nxt = (l1 & 1) ? ldsA : ldsB;
      const int Wn = Wc >> 1;
      const int units = 8 * Wn * 2;
      for (int u = t; u < units; u += 256) {
        int k = u & 1;
        int xr = u >> 1;
        int x = xr & (Wn - 1);
        int r = xr >> (6 - l1);
        uint4 a = cur[(r * Wc + 2 * x) * 2 + k];
        uint4 c = cur[(r * Wc + 2 * x + 1) * 2 + k];
        nxt[(r * Wn + x) * 2 + k] = havg(a, c, hhalf);
      }
    }

    if (l1 >= 1) {
      const int slots = Wc * 2;
      if (t < slots) {
        int k = t & 1, x = t >> 1;
        const int Wg = 512 >> l1;
        uint4 r0 = cur[(0 * Wc + x) * 2 + k];
        uint4 r1 = cur[(1 * Wc + x) * 2 + k];
        uint4 r2 = cur[(2 * Wc + x) * 2 + k];
        uint4 r3 = cur[(3 * Wc + x) * 2 + k];
        uint4 r4 = cur[(4 * Wc + x) * 2 + k];
        uint4 r5 = cur[(5 * Wc + x) * 2 + k];
        uint4 r6 = cur[(6 * Wc + x) * 2 + k];
        uint4 r7 = cur[(7 * Wc + x) * 2 + k];
        uint4 a0 = havg(r0, r1, hhalf), a1 = havg(r2, r3, hhalf);
        uint4 a2 = havg(r4, r5, hhalf), a3 = havg(r6, r7, hhalf);
        uint4 b0 = havg(a0, a1, hhalf), b1 = havg(a2, a3, hhalf);
        uint4 c0 = havg(b0, b1, hhalf);
        int gx = s * Wc + x;
        long p1 = (long)offp_a(l1, 1) + (long)(b * 4) * Wg + gx;
        bv4[p1 * 2 + k] = a0;
        bv4[(p1 + Wg) * 2 + k] = a1;
        bv4[(p1 + 2 * Wg) * 2 + k] = a2;
        bv4[(p1 + 3 * Wg) * 2 + k] = a3;
        long p2 = (long)offp_a(l1, 2) + (long)(b * 2) * Wg + gx;
        bv4[p2 * 2 + k] = b0;
        bv4[(p2 + Wg) * 2 + k] = b1;
        long p3 = (long)offp_a(l1, 3) + (long)b * Wg + gx;
        bv4[p3 * 2 + k] = c0;
      }
    }
    __syncthreads();
  }
}

// ---- pool tail (single launch): levels (l1,4..7) from (l1,3), l1>=1 ----
template<int L2SRC, int NLEV>
__global__ __launch_bounds__(256) void pool_hN(__half* __restrict__ pyr)
{
  constexpr int R = 1 << NLEV;
  constexpr int HL = 512 >> (L2SRC + NLEV);
  int total = NV * HL * 1016;
  int t = blockIdx.x * 256 + threadIdx.x;
  if (t >= total) return;
  int u = t % 1016;
  int r2 = t / 1016;
  int c = 512 + (u >> 1), k = u & 1;
  int y = r2 % HL;
  int v = r2 / HL;
  int l1 = 0;
  #pragma unroll
  for (int i = 1; i < 8; ++i) l1 += (c >= c_CW[i]) ? 1 : 0;
  int x = c - c_CW[l1];
  int W = 512 >> l1;
  __half* bv = pyr + (long)v * PYR_PX * FD;
  const __half* src = bv + (long)offp_a(l1, L2SRC) * FD;

  uint4 d[R];
  long base = ((long)(y * R) * W + x) * FD + k * 8;
  #pragma unroll
  for (int r = 0; r < R; ++r)
    d[r] = *(const uint4*)(src + base + (long)r * W * FD);

  const __half2 hhalf = __floats2half2_rn(0.5f, 0.5f);
  #pragma unroll
  for (int lev = 1; lev <= NLEV; ++lev) {
    int cnt = R >> lev;
    __half* dst = bv + (long)offp_a(l1, L2SRC + lev) * FD;
    #pragma unroll
    for (int r = 0; r < cnt; ++r) {
      d[r] = havg(d[2 * r], d[2 * r + 1], hhalf);
      *(uint4*)(dst + (((long)(y * cnt + r)) * W + x) * FD + k * 8) = d[r];
    }
  }
}

// ---- dup build ----
__global__ __launch_bounds__(256) void build_dup(__half* __restrict__ pyr)
{
  int cb = blockIdx.y;
  int l1 = 2 + (cb >> 2), l2 = 2 + (cb & 3);
  int W = 512 >> l1, H = 512 >> l2;
  int units = NV * W * H * 2;
  int gx = blockIdx.x * 256 + threadIdx.x;
  if (gx >= units) return;
  int k = gx & 1;
  int p = gx >> 1;
  int x = p & (W - 1);
  int r = p >> (9 - l1);
  int y = r & (H - 1);
  int v = r >> (9 - l2);
  long srcPx = (long)v * PYR_PX + offp_a(l1, l2) + y * W + min(x + 1, W - 1);
  int Ad = 61440 - (245760 >> l1);
  int Bd = 256 - (1024 >> l2);
  long dstPx = (long)DUP0_PX + (long)v * DUP_VPX + Ad + ((Bd + y) << (9 - l1)) + x;
  const uint4* src = (const uint4*)(pyr + srcPx * FD);
  uint4* dst = (uint4*)(pyr + dstPx * FD);
  dst[k] = src[k];
}

// ---- proj + block-aggregated rare-pair flagging ----
__global__ __launch_bounds__(256) void proj_kernel(const float* __restrict__ means,
                                                   const float* __restrict__ covs,
                                                   float4* __restrict__ pl,
                                                   int* __restrict__ cnt,
                                                   int* __restrict__ list)
{
  __shared__ int lbuf[2560];
  __shared__ int lcnt, lbase;
  if (threadIdx.x == 0) lcnt = 0;
  __syncthreads();
  int n = blockIdx.x * 256 + threadIdx.x;   // NS = 1024*256 exactly
  float m0 = means[3 * n], m1 = means[3 * n + 1], m2 = means[3 * n + 2];
  const float* C = covs + 9L * n;
  float c0 = C[0], c1 = C[1], c2 = C[2];
  float c3 = C[3], c4 = C[4], c5 = C[5];
  float c6 = C[6], c7 = C[7], c8 = C[8];
  #pragma unroll
  for (int v = 0; v < NV; ++v) {
    float p00 = c_P[v][0][0], p01 = c_P[v][0][1], p02 = c_P[v][0][2];
    float p10 = c_P[v][1][0], p11 = c_P[v][1][1], p12 = c_P[v][1][2];
    float cx = m0 * p00 + m1 * p01 + m2 * p02;
    float cy = m0 * p10 + m1 * p11 + m2 * p12;
    float t0 = c0 * p00 + c1 * p01 + c2 * p02;
    float t1 = c3 * p00 + c4 * p01 + c5 * p02;
    float t2 = c6 * p00 + c7 * p01 + c8 * p02;
    float s2x = p00 * t0 + p01 * t1 + p02 * t2;
    t0 = c0 * p10 + c1 * p11 + c2 * p12;
    t1 = c3 * p10 + c4 * p11 + c5 * p12;
    t2 = c6 * p10 + c7 * p11 + c8 * p12;
    float s2y = p10 * t0 + p11 * t1 + p12 * t2;
    float lx = 0.5f * log2f(fmaxf(s2x, 1e-20f)) + 9.0f;
    float ly = 0.5f * log2f(fmaxf(s2y, 1e-20f)) + 9.0f;
    lx = fminf(fmaxf(lx, 0.0f), 7.0f);
    ly = fminf(fmaxf(ly, 0.0f), 7.0f);
    pl[(long)v * NS + n] = make_float4(cx, cy, lx, ly);
    if (lx < 1.0f || ly < 1.0f) {
      int pos = atomicAdd(&lcnt, 1);
      lbuf[pos] = v * NS + n;
    }
  }
  __syncthreads();
  if (threadIdx.x == 0) lbase = atomicAdd(cnt, lcnt);
  __syncthreads();
  for (int i = threadIdx.x; i < lcnt; i += 256) list[lbase + i] = lbuf[i];
}

// ---- per-pair tap context (fast path) ----
struct Ctx {
  int oA, oB, oC, oD, oE, oF, oG, oH;
  __half2 wA, wB, wC, wD, wE, wF, wG, wH;
};

__device__ __forceinline__ Ctx mk_ctx(const float4 p, const bool qodd,
                                      const int dupRel)
{
  Ctx c;
  float cx = p.x, cy = p.y, lx = p.z, ly = p.w;
  int l1f = (int)lx, l2f = (int)ly;
  float wx = lx - (float)l1f, wy = ly - (float)l2f;
  int l1c = min(l1f + 1, 7);
  int l2c = min(l2f + 1, 7);

  int sh_0 = 9 - l1f;
  int Ar_0 = 1044480 - (1020 << (10 - l1f));
  float u0 = (cx * 0.5f + 0.5f) * (float)(1 << sh_0) - 0.5f;
  float uf0 = floorf(u0);
  float fu0 = u0 - uf0;
  int iu0 = (int)uf0;
  bool e0 = (iu0 < 0) || (iu0 >= (1 << sh_0) - 1);
  int ix_0 = min(max(iu0, 0), (1 << sh_0) - 1);
  float wxl_0 = qodd ? (e0 ? 0.0f : fu0) : (e0 ? 1.0f : 1.0f - fu0);
  int pOdd_0 = ix_0 & 1;
  int Ad_0 = 61440 - (245760 >> l1f);
  int inR1_0 = ((unsigned)(l1f - 2) <= 3u) ? 1 : 0;

  int sh_1 = 9 - l1c;
  int Ar_1 = 1044480 - (1020 << (10 - l1c));
  float u1 = (cx * 0.5f + 0.5f) * (float)(1 << sh_1) - 0.5f;
  float uf1 = floorf(u1);
  float fu1 = u1 - uf1;
  int iu1 = (int)uf1;
  bool e1 = (iu1 < 0) || (iu1 >= (1 << sh_1) - 1);
  int ix_1 = min(max(iu1, 0), (1 << sh_1) - 1);
  float wxl_1 = qodd ? (e1 ? 0.0f : fu1) : (e1 ? 1.0f : 1.0f - fu1);
  int pOdd_1 = ix_1 & 1;
  int Ad_1 = 61440 - (245760 >> l1c);
  int inR1_1 = ((unsigned)(l1c - 2) <= 3u) ? 1 : 0;

  float wl1_0 = 1.0f - wx, wl1_1 = wx;

  int H0 = 512 >> l2f;
  float vv0 = (cy * 0.5f + 0.5f) * (float)H0 - 0.5f;
  float vf0 = floorf(vv0);
  float fv_0 = vv0 - vf0;
  int iv0 = (int)vf0;
  int iy_0 = min(max(iv0, 0), H0 - 1);
  int dy_0 = min(max(iv0 + 1, 0), H0 - 1) - iy_0;
  int Bv_0 = 1024 - (1024 >> l2f);
  int Bd_0 = 256 - (1024 >> l2f);
  int inR2_0 = ((unsigned)(l2f - 2) <= 3u) ? 1 : 0;

  int H1 = 512 >> l2c;
  float vv1 = (cy * 0.5f + 0.5f) * (float)H1 - 0.5f;
  float vf1 = floorf(vv1);
  float fv_1 = vv1 - vf1;
  int iv1 = (int)vf1;
  int iy_1 = min(max(iv1, 0), H1 - 1);
  int dy_1 = min(max(iv1 + 1, 0), H1 - 1) - iy_1;
  int Bv_1 = 1024 - (1024 >> l2c);
  int Bd_1 = 256 - (1024 >> l2c);
  int inR2_1 = ((unsigned)(l2c - 2) <= 3u) ? 1 : 0;

  float wl2_0 = 1.0f - wy, wl2_1 = wy;

  bool s00 = pOdd_0 && inR1_0 && inR2_0;
  c.oA = s00 ? (dupRel + Ad_0 + ((Bd_0 + iy_0) << sh_0) + ix_0 - 1)
             : (Ar_0 + ((Bv_0 + iy_0) << sh_0) + ix_0);
  c.oB = c.oA + (dy_0 << sh_0);
  bool s01 = pOdd_0 && inR1_0 && inR2_1;
  c.oC = s01 ? (dupRel + Ad_0 + ((Bd_1 + iy_1) << sh_0) + ix_0 - 1)
             : (Ar_0 + ((Bv_1 + iy_1) << sh_0) + ix_0);
  c.oD = c.oC + (dy_1 << sh_0);
  bool s10 = pOdd_1 && inR1_1 && inR2_0;
  c.oE = s10 ? (dupRel + Ad_1 + ((Bd_0 + iy_0) << sh_1) + ix_1 - 1)
             : (Ar_1 + ((Bv_0 + iy_0) << sh_1) + ix_1);
  c.oF = c.oE + (dy_0 << sh_1);
  bool s11 = pOdd_1 && inR1_1 && inR2_1;
  c.oG = s11 ? (dupRel + Ad_1 + ((Bd_1 + iy_1) << sh_1) + ix_1 - 1)
             : (Ar_1 + ((Bv_1 + iy_1) << sh_1) + ix_1);
  c.oH = c.oG + (dy_1 << sh_1);

  float wb00 = wl1_0 * wl2_0 * wxl_0;
  float wb01 = wl1_0 * wl2_1 * wxl_0;
  float wb10 = wl1_1 * wl2_0 * wxl_1;
  float wb11 = wl1_1 * wl2_1 * wxl_1;
  c.wA = __float2half2_rn(wb00 * (1.0f - fv_0));
  c.wB = __float2half2_rn(wb00 * fv_0);
  c.wC = __float2half2_rn(wb01 * (1.0f - fv_1));
  c.wD = __float2half2_rn(wb01 * fv_1);
  c.wE = __float2half2_rn(wb10 * (1.0f - fv_0));
  c.wF = __float2half2_rn(wb10 * fv_0);
  c.wG = __float2half2_rn(wb11 * (1.0f - fv_1));
  c.wH = __float2half2_rn(wb11 * fv_1);

  // rare pairs (level-0 combos) fully recomputed by fixup2; zero weights here
  __half2 z = __float2half2_rn(0.0f);
  if (l1f == 0) { c.wA = z; c.wB = z; c.wC = z; c.wD = z; }
  if (l2f == 0) { c.wA = z; c.wB = z; c.wE = z; c.wF = z; }
  return c;
}

// ---- interp: 4 lanes/pair, 2 pairs/thread ----
__global__ __launch_bounds__(256) void interp8(const float4* __restrict__ pl,
                                               const __half* __restrict__ pyr,
                                               float* __restrict__ out)
{
  int bid = blockIdx.x;
  int swz = (bid & 7) * 2560 + (bid >> 3);
  int t = swz * 256 + threadIdx.x;
  int q = t & 3;
  bool qodd = (q & 1);
  int vlow = (t >> 2) & 1;
  int n = (t >> 3) & (HALF_NS - 1);
  int v2 = t >> 20;
  int v = v2 * 2 + vlow;
  int nA = n, nB = n + HALF_NS;
  int dupRel = DUP0_PX + v * DUP_VPX - v * 1040400;

  float4 pA = pl[(long)v * NS + nA];
  float4 pB = pl[(long)v * NS + nB];

  const __half* bvq = pyr + (long)v * PYR_PX * FD + ((q & 1) * 16 + (q >> 1) * 8);

  Ctx cA = mk_ctx(pA, qodd, dupRel);
  uint4 dAA = *(const uint4*)(bvq + (long)cA.oA * FD);
  uint4 dAB = *(const uint4*)(bvq + (long)cA.oB * FD);
  uint4 dAC = *(const uint4*)(bvq + (long)cA.oC * FD);
  uint4 dAD = *(const uint4*)(bvq + (long)cA.oD * FD);
  uint4 dAE = *(const uint4*)(bvq + (long)cA.oE * FD);
  uint4 dAF = *(const uint4*)(bvq + (long)cA.oF * FD);
  uint4 dAG = *(const uint4*)(bvq + (long)cA.oG * FD);
  uint4 dAH = *(const uint4*)(bvq + (long)cA.oH * FD);

  Ctx cB = mk_ctx(pB, qodd, dupRel);
  uint4 dBA = *(const uint4*)(bvq + (long)cB.oA * FD);
  uint4 dBB = *(const uint4*)(bvq + (long)cB.oB * FD);
  uint4 dBC = *(const uint4*)(bvq + (long)cB.oC * FD);
  uint4 dBD = *(const uint4*)(bvq + (long)cB.oD * FD);
  uint4 dBE = *(const uint4*)(bvq + (long)cB.oE * FD);
  uint4 dBF = *(const uint4*)(bvq + (long)cB.oF * FD);
  uint4 dBG = *(const uint4*)(bvq + (long)cB.oG * FD);
  uint4 dBH = *(const uint4*)(bvq + (long)cB.oH * FD);
  __builtin_amdgcn_sched_barrier(0);

  __half2 z = __float2half2_rn(0.0f);
  __half2 aA0 = z, aA1 = z, aA2 = z, aA3 = z;
  __half2 aB0 = z, aB1 = z, aB2 = z, aB3 = z;
  #define ACC8(A0, A1, A2, A3, D, W) { const __half2* hh = (const __half2*)&(D); \
    A0 = __hfma2(hh[0], (W), A0); A1 = __hfma2(hh[1], (W), A1);                   \
    A2 = __hfma2(hh[2], (W), A2); A3 = __hfma2(hh[3], (W), A3); }
  ACC8(aA0,aA1,aA2,aA3, dAA, cA.wA) ACC8(aA0,aA1,aA2,aA3, dAB, cA.wB)
  ACC8(aA0,aA1,aA2,aA3, dAC, cA.wC) ACC8(aA0,aA1,aA2,aA3, dAD, cA.wD)
  ACC8(aA0,aA1,aA2,aA3, dAE, cA.wE) ACC8(aA0,aA1,aA2,aA3, dAF, cA.wF)
  ACC8(aA0,aA1,aA2,aA3, dAG, cA.wG) ACC8(aA0,aA1,aA2,aA3, dAH, cA.wH)
  ACC8(aB0,aB1,aB2,aB3, dBA, cB.wA) ACC8(aB0,aB1,aB2,aB3, dBB, cB.wB)
  ACC8(aB0,aB1,aB2,aB3, dBC, cB.wC) ACC8(aB0,aB1,aB2,aB3, dBD, cB.wD)
  ACC8(aB0,aB1,aB2,aB3, dBE, cB.wE) ACC8(aB0,aB1,aB2,aB3, dBF, cB.wF)
  ACC8(aB0,aB1,aB2,aB3, dBG, cB.wG) ACC8(aB0,aB1,aB2,aB3, dBH, cB.wH)
  #undef ACC8

  #define XC(A0, A1, A2, A3) {                                   \
    int x0 = *(int*)&A0, x1 = *(int*)&A1;                        \
    int x2 = *(int*)&A2, x3 = *(int*)&A3;                        \
    int y0 = __shfl_xor(x0, 1), y1 = __shfl_xor(x1, 1);          \
    int y2 = __shfl_xor(x2, 1), y3 = __shfl_xor(x3, 1);          \
    A0 = __hadd2(A0, *(__half2*)&y0); A1 = __hadd2(A1, *(__half2*)&y1); \
    A2 = __hadd2(A2, *(__half2*)&y2); A3 = __hadd2(A3, *(__half2*)&y3); }
  XC(aA0, aA1, aA2, aA3)
  XC(aB0, aB1, aB2, aB3)
  #undef XC

  __half2 sA0 = qodd ? aA2 : aA0;
  __half2 sA1 = qodd ? aA3 : aA1;
  float2 fA0 = __half22float2(sA0);
  float2 fA1 = __half22float2(sA1);
  *(float4*)(out + ((long)nA * NV + v) * FD + q * 4) =
      make_float4(fA0.x, fA0.y, fA1.x, fA1.y);

  __half2 sB0 = qodd ? aB2 : aB0;
  __half2 sB1 = qodd ? aB3 : aB1;
  float2 fB0 = __half22float2(sB0);
  float2 fB1 = __half22float2(sB1);
  *(float4*)(out + ((long)nB * NV + v) * FD + q * 4) =
      make_float4(fB0.x, fB0.y, fB1.x, fB1.y);
}

// ---- fixup2: one 64-lane wave per flagged pair ----
__global__ __launch_bounds__(256) void fixup2(const float4* __restrict__ pl,
                                              const __half* __restrict__ pyr,
                                              const float* __restrict__ fm,
                                              const int* __restrict__ cnt,
                                              const int* __restrict__ list,
                                              float* __restrict__ out)
{
  int nfix = *cnt;
  int lane = threadIdx.x & 63;
  int wid = (blockIdx.x * 256 + threadIdx.x) >> 6;
  int nw = (gridDim.x * 256) >> 6;
  int k  = lane & 1;
  int h  = (lane >> 1) & 1;
  int xs = (lane >> 2) & 1;
  int r  = (lane >> 3) & 1;
  int jj = (lane >> 4) & 1;
  int ii = (lane >> 5) & 1;

  for (int idx = wid; idx < nfix; idx += nw) {
    int pv = list[idx];
    int v = pv >> 18, n = pv & (NS - 1);
    float4 p = pl[(long)pv];
    float cx = p.x, cy = p.y, lx = p.z, ly = p.w;
    int l1f = (int)lx, l2f = (int)ly;
    float wx = lx - (float)l1f, wy = ly - (float)l2f;
    int l1 = ii ? min(l1f + 1, 7) : l1f;
    int l2 = jj ? min(l2f + 1, 7) : l2f;
    float wl1 = ii ? wx : 1.0f - wx;
    float wl2 = jj ? wy : 1.0f - wy;
    int Wl = 512 >> l1, Hl = 512 >> l2;

    float u = (cx * 0.5f + 0.5f) * (float)Wl - 0.5f;
    float uf = floorf(u);
    float fu = u - uf;
    int iu = (int)uf;
    int ix0 = min(max(iu, 0), Wl - 1);
    int ix1 = min(max(iu + 1, 0), Wl - 1);
    int ix = xs ? ix1 : ix0;
    float wxs = xs ? fu : 1.0f - fu;

    float vv = (cy * 0.5f + 0.5f) * (float)Hl - 0.5f;
    float vf = floorf(vv);
    float fv = vv - vf;
    int iv = (int)vf;
    int iy0 = min(max(iv, 0), Hl - 1);
    int iy1 = min(max(iv + 1, 0), Hl - 1);
    int iy = r ? iy1 : iy0;
    float wys = r ? fv : 1.0f - fv;

    float w = wl1 * wl2 * wxs * wys;
    float s0=0,s1=0,s2=0,s3=0,s4=0,s5=0,s6=0,s7=0;

    const float* fmb = fm + (long)v * (262144L * FD) + h * 8;
    if (l1 > 0 && l2 > 0) {
      if (k == 0) {
        const __half* pp = pyr + ((long)v * PYR_PX + offp_a(l1, l2) +
                                  (long)iy * Wl + ix) * FD + h * 8;
        uint4 d = *(const uint4*)pp;
        const __half2* hh = (const __half2*)&d;
        float2 f0 = __half22float2(hh[0]), f1 = __half22float2(hh[1]);
        float2 f2 = __half22float2(hh[2]), f3 = __half22float2(hh[3]);
        s0=f0.x; s1=f0.y; s2=f1.x; s3=f1.y; s4=f2.x; s5=f2.y; s6=f3.x; s7=f3.y;
      }
    } else if (l1 == 0 && l2 == 0) {
      if (k == 0) {
        const float* s = fmb + ((long)iy * 512 + ix) * FD;
        float4 g0 = *(const float4*)s, g1 = *(const float4*)(s + 4);
        s0=g0.x; s1=g0.y; s2=g0.z; s3=g0.w; s4=g1.x; s5=g1.y; s6=g1.z; s7=g1.w;
      }
    } else if (l2 == 0) {                 // l1>=1: average 2^l1 fm columns
      int m = 1 << l1, base = ix << l1;
      for (int e = k; e < m; e += 2) {
        const float* s = fmb + ((long)iy * 512 + base + e) * FD;
        float4 g0 = *(const float4*)s, g1 = *(const float4*)(s + 4);
        s0+=g0.x; s1+=g0.y; s2+=g0.z; s3+=g0.w;
        s4+=g1.x; s5+=g1.y; s6+=g1.z; s7+=g1.w;
      }
      float inv = 1.0f / (float)m;
      s0*=inv; s1*=inv; s2*=inv; s3*=inv; s4*=inv; s5*=inv; s6*=inv; s7*=inv;
    } else {                              // l1==0, l2>=1: average 2^l2 fm rows
      int m = 1 << l2, base = iy << l2;
      for (int e = k; e < m; e += 2) {
        const float* s = fmb + ((long)(base + e) * 512 + ix) * FD;
        float4 g0 = *(const float4*)s, g1 = *(const float4*)(s + 4);
        s0+=g0.x; s1+=g0.y; s2+=g0.z; s3+=g0.w;
        s4+=g1.x; s5+=g1.y; s6+=g1.z; s7+=g1.w;
      }
      float inv = 1.0f / (float)m;
      s0*=inv; s1*=inv; s2*=inv; s3*=inv; s4*=inv; s5*=inv; s6*=inv; s7*=inv;
    }

    float a0=w*s0, a1=w*s1, a2=w*s2, a3=w*s3;
    float a4=w*s4, a5=w*s5, a6=w*s6, a7=w*s7;

    #define RED(M) { a0 += __shfl_xor(a0, M); a1 += __shfl_xor(a1, M); \
      a2 += __shfl_xor(a2, M); a3 += __shfl_xor(a3, M);                \
      a4 += __shfl_xor(a4, M); a5 += __shfl_xor(a5, M);                \
      a6 += __shfl_xor(a6, M); a7 += __shfl_xor(a7, M); }
    RED(1) RED(4) RED(8) RED(16) RED(32)
    #undef RED

    if (lane == 0 || lane == 2) {         // h = 0 / 1
      float* o = out + ((long)n * NV + v) * FD + h * 8;
      *(float4*)o = make_float4(a0, a1, a2, a3);
      *(float4*)(o + 4) = make_float4(a4, a5, a6, a7);
    }
  }
}

extern "C" void kernel_launch(void* const* d_in, const int* in_sizes, int n_in,
                              void* d_out, int out_size, void* d_ws, size_t ws_size,
                              hipStream_t stream)
{
  const float* means = (const float*)d_in[0];
  const float* covs  = (const float*)d_in[1];
  const float* fm    = (const float*)d_in[2];
  float* out = (float*)d_out;
  __half* pyr = (__half*)d_ws;
  float4* pl  = (float4*)((char*)d_ws + OFF_PL);
  int* cnt    = (int*)((char*)d_ws + OFF_CNT);
  int* list   = (int*)((char*)d_ws + OFF_LIST);

  build_all<<<NV * 256, 256, 0, stream>>>(fm, pyr, cnt);
  {
    int tB = NV * 4 * 1016;    // levels 4..7 from 3 (l1>=1), single launch
    pool_hN<3, 4><<<(tB + 255) / 256, 256, 0, stream>>>(pyr);
  }
  {
    dim3 g(1280, 16, 1);
    build_dup<<<g, 256, 0, stream>>>(pyr);
  }
  proj_kernel<<<NS / 256, 256, 0, stream>>>(means, covs, pl, cnt, list);

  interp8<<<20480, 256, 0, stream>>>(pl, pyr, out);
  fixup2<<<4096, 256, 0, stream>>>(pl, pyr, fm, cnt, list, out);
}